// Round 8
// baseline (228.273 us; speedup 1.0000x reference)
//
#include <hip/hip_runtime.h>
#include <math.h>

// Problem constants
#define B_DIM 8
#define T_DIM 2048
#define C_DIM 1024
#define HS_DIM 128
#define VD 256
#define M_DIM (B_DIM * T_DIM)            // 16384 rows
#define QK_ELEMS (M_DIM * HS_DIM)        // 2,097,152 elems per (q|k) term
#define SCALE 0.088388347648318447f      // 1/sqrt(128)
#define LOG_THETA 9.210340371976184f     // ln(10000)

// workspace layout (ushort units)
#define QB_OFF   0u
#define KB_OFF   4194304u
#define VT_OFF   8388608u
#define WT_OFF   12582912u
#define XBH_OFF  13369344u               // x-bf16 rows 8192..16383
#define LAM_OFF  21757952u
#define XSPLIT_ELEMS 8388608u            // rows 0..8191 of x-bf16 live in d_out

typedef short s8v   __attribute__((ext_vector_type(8)));   // 8 bf16 (4 VGPRs)
typedef float f32x4 __attribute__((ext_vector_type(4)));
typedef float f32x16 __attribute__((ext_vector_type(16)));

// ---------- helpers ----------
__device__ __forceinline__ unsigned int bf16_rne(float f) {
    unsigned int u = __float_as_uint(f);
    return (u + 0x7fffu + ((u >> 16) & 1u)) >> 16;
}
__device__ __forceinline__ unsigned int pack_bf2(float lo, float hi) {
    return bf16_rne(lo) | (bf16_rne(hi) << 16);
}
__device__ __forceinline__ void async_cp16(const unsigned short* g, unsigned short* l) {
    __builtin_amdgcn_global_load_lds(
        (const __attribute__((address_space(1))) unsigned int*)g,
        (__attribute__((address_space(3))) unsigned int*)l, 16, 0, 0);
}

// ---------- kernel 1: lambda coefficients ----------
__global__ void lam_kernel(const float* __restrict__ lq, const float* __restrict__ lk,
                           const int* __restrict__ lidx, float* __restrict__ lam_out) {
    int t = threadIdx.x; // 64 threads = 1 wave
    float s0 = expf(lq[t] * lk[t]) + expf(lq[t + 64] * lk[t + 64]);
    float s1 = expf(lq[128 + t] * lk[128 + t]) + expf(lq[192 + t] * lk[192 + t]);
    #pragma unroll
    for (int off = 32; off > 0; off >>= 1) {
        s0 += __shfl_down(s0, off);
        s1 += __shfl_down(s1, off);
    }
    if (t == 0) {
        float e0 = s0 * (1.0f / 128.0f);
        float e1 = s1 * (1.0f / 128.0f);
        float li = 0.8f - 0.6f * expf(-0.3f * ((float)lidx[0] - 1.0f));
        lam_out[0] = e0 + li;            // +lam0
        lam_out[1] = -(e1 - e0 + li);    // -lam1
    }
}

// ---------- kernel 2a: cast x -> bf16 (split across d_out scratch + ws) ----------
__global__ __launch_bounds__(256) void cast_x_kernel(const float* __restrict__ x,
                                                     unsigned short* __restrict__ lo,
                                                     unsigned short* __restrict__ hi) {
    const size_t i8 = ((size_t)blockIdx.x * 256 + threadIdx.x) * 8;
    float4 a = *(const float4*)(x + i8);
    float4 b = *(const float4*)(x + i8 + 4);
    uint4 u;
    u.x = pack_bf2(a.x, a.y); u.y = pack_bf2(a.z, a.w);
    u.z = pack_bf2(b.x, b.y); u.w = pack_bf2(b.z, b.w);
    unsigned short* dst = (i8 < XSPLIT_ELEMS) ? (lo + i8) : (hi + (i8 - XSPLIT_ELEMS));
    *(uint4*)dst = u;
}

// ---------- kernel 2b: build Wt[768][1024] bf16 (transposed, concatenated) ----
// Q/K segments (seg 0..3) store PERMUTED columns: position n holds source dim
// pi(n) = 2*((n&15)+((n>>5)<<4)) + ((n>>4)&1)  (bijection per 128-col segment).
// This puts each RoPE rotation pair (2m,2m+1) into ONE lane's (j,j+1) MFMA
// register pair in the gemm epilogue -> RoPE with zero cross-lane shfl.
// V segments (seg 4..5) unpermuted.
__global__ __launch_bounds__(256) void cast_wt_kernel(
    const float* __restrict__ Wq, const float* __restrict__ Wk,
    const float* __restrict__ Wv, unsigned short* __restrict__ wt) {
    __shared__ float tile[32][33];
    const int t = threadIdx.x;
    const int n0 = blockIdx.x * 32;
    const int k0 = blockIdx.y * 32;
    const int seg = n0 >> 7;
    const int nl = t & 31;
    const int ng = n0 + nl;
    const int ngl = ng & 127;
    const int pcol = 2 * ((ngl & 15) + ((ngl >> 5) << 4)) + ((ngl >> 4) & 1);
    const float* src; int ld;
    if (seg < 2)      { src = Wq + (size_t)seg * (C_DIM * HS_DIM) + pcol; ld = 128; }
    else if (seg < 4) { src = Wk + (size_t)(seg - 2) * (C_DIM * HS_DIM) + pcol; ld = 128; }
    else              { src = Wv + (ng - 512); ld = 256; }
    #pragma unroll
    for (int rep = 0; rep < 4; ++rep) {
        int kl = (t >> 5) + rep * 8;
        tile[kl][nl] = src[(size_t)(k0 + kl) * ld];
    }
    __syncthreads();
    unsigned int* wt32 = (unsigned int*)wt;
    #pragma unroll
    for (int rep = 0; rep < 2; ++rep) {
        int nl2 = (t >> 4) + rep * 16;
        int k2 = (t & 15) * 2;
        unsigned int u = pack_bf2(tile[k2][nl2], tile[k2 + 1][nl2]);
        wt32[((size_t)(n0 + nl2) * 1024 + k0 + k2) >> 1] = u;
    }
}

// ---------- kernel 2c: bf16 MFMA GEMM + RoPE / V-transpose epilogue ----------
// RoPE epilogue: with the Wt column permutation, lane (wc,l15) reg-pair
// (j,j+1) holds dims (2*mi, 2*mi+1), mi = l15 + 16*(j>>1) + 32*wc. RoPE is
// in-lane: out_r = xr*cs - xi*sn, out_i = xr*sn + xi*cs, one coalesced u32
// store per pair (zero cross-lane shfl, half the sincos).
__global__ __launch_bounds__(256) void gemm_kernel(
    const unsigned short* __restrict__ xlo, const unsigned short* __restrict__ xhi,
    const unsigned short* __restrict__ wt,
    unsigned short* __restrict__ qo, unsigned short* __restrict__ ko,
    unsigned short* __restrict__ vo) {
    __shared__ unsigned short As[128 * 32];   // 8 KB, row-major [128][32]
    __shared__ unsigned short Bs[128 * 32];   // 8 KB, row-major [128][32]

    const int t = threadIdx.x;
    const int wv = t >> 6, lane = t & 63;
    const int quad = lane >> 4, l15 = lane & 15;
    const int m0 = blockIdx.x * 128;
    const int n0 = blockIdx.y * 128;
    const int wr = wv >> 1, wc = wv & 1;

    const unsigned short* xbase = (m0 < 8192)
        ? (xlo + (size_t)m0 * C_DIM) : (xhi + (size_t)(m0 - 8192) * C_DIM);

    f32x4 acc[4][4];
    #pragma unroll
    for (int i = 0; i < 4; ++i)
        #pragma unroll
        for (int j = 0; j < 4; ++j) acc[i][j] = (f32x4){0.f, 0.f, 0.f, 0.f};

    const int srow = lane >> 2;
    const int skof = (lane & 3) * 8;

    for (int k0 = 0; k0 < C_DIM; k0 += 32) {
        #pragma unroll
        for (int j = 0; j < 2; ++j) {
            const int c = wv * 2 + j;
            async_cp16(xbase + (size_t)(c * 16 + srow) * C_DIM + k0 + skof, As + c * 512);
        }
        #pragma unroll
        for (int j = 0; j < 2; ++j) {
            const int c = wv * 2 + j;
            async_cp16(wt + (size_t)(n0 + c * 16 + srow) * C_DIM + k0 + skof, Bs + c * 512);
        }
        __syncthreads();
        s8v af[4], bf[4];
        #pragma unroll
        for (int i = 0; i < 4; ++i)
            af[i] = *(const s8v*)&As[(wr * 64 + i * 16 + l15) * 32 + quad * 8];
        #pragma unroll
        for (int j = 0; j < 4; ++j)
            bf[j] = *(const s8v*)&Bs[(wc * 64 + j * 16 + l15) * 32 + quad * 8];
        #pragma unroll
        for (int i = 0; i < 4; ++i)
            #pragma unroll
            for (int j = 0; j < 4; ++j)
                acc[i][j] = __builtin_amdgcn_mfma_f32_16x16x32_bf16(af[i], bf[j], acc[i][j], 0, 0, 0);
        __syncthreads();
    }

    const int seg = n0 >> 7;   // 0..5
    if (seg < 4) {
        unsigned short* dstbuf = ((seg < 2) ? qo : ko) + (size_t)(seg & 1) * QK_ELEMS;
        // pair-index (= d>>1) for j-pairs (0,1) and (2,3)
        const int mi0 = l15 + 32 * wc;
        const int mi1 = mi0 + 16;
        const float freq0 = __expf((float)mi0 * (-LOG_THETA / 64.f));
        const float freq1 = __expf((float)mi1 * (-LOG_THETA / 64.f));
        #pragma unroll
        for (int i = 0; i < 4; ++i) {
            #pragma unroll
            for (int e = 0; e < 4; ++e) {
                const int m = m0 + wr * 64 + i * 16 + quad * 4 + e;
                const float trow = (float)(m & (T_DIM - 1));
                unsigned int* p32 = (unsigned int*)(dstbuf + (size_t)m * HS_DIM);
                float sn0, cs0, sn1, cs1;
                __sincosf(trow * freq0, &sn0, &cs0);
                __sincosf(trow * freq1, &sn1, &cs1);
                const float xr0 = acc[i][0][e], xi0 = acc[i][1][e];
                const float xr1 = acc[i][2][e], xi1 = acc[i][3][e];
                p32[mi0] = pack_bf2(xr0 * cs0 - xi0 * sn0, xr0 * sn0 + xi0 * cs0);
                p32[mi1] = pack_bf2(xr1 * cs1 - xi1 * sn1, xr1 * sn1 + xi1 * cs1);
            }
        }
    } else {
        const int bq = m0 >> 11;
        const int tbase = m0 & (T_DIM - 1);
        unsigned int* vT32 = (unsigned int*)vo;
        #pragma unroll
        for (int j = 0; j < 4; ++j) {
            const int d = (seg - 4) * 128 + wc * 64 + j * 16 + l15;
            const size_t rowbase = (size_t)(bq * VD + d) * (T_DIM / 2); // u32 units
            #pragma unroll
            for (int i = 0; i < 4; ++i) {
                const int tok = tbase + wr * 64 + i * 16 + quad * 4;
                uint2 u;
                u.x = pack_bf2(acc[i][j][0], acc[i][j][1]);
                u.y = pack_bf2(acc[i][j][2], acc[i][j][3]);
                *(uint2*)&vT32[rowbase + (tok >> 1)] = u;
            }
        }
    }
}

// ---------- kernel 3: dual-term causal attention, 32x32 bf16 MFMA ----------
// Round-8: MERGED complementary pair. Grid: 256 blocks = 32 pairs x 8
// batches; block = 512 threads / 8 waves handling strips (63-k, k). The
// light strip's key range is a subset of the heavy's, so K/V tiles are
// staged ONCE per block and consumed by both strips -> per-CU staged bytes
// per tile halve (128 KB -> 64 KB; this was the dominant serialized term:
// >=2300 cyc of L2->CU transfer per tile-pair in the R0 layout).
// Wave w: sg = w>>2 (strip), term = w&1, kh = (w>>1)&1. Per-wave compute,
// registers, and LDS phase layouts are R0-verbatim for its strip. Strip
// participation is wave-uniform (it < ntS) -> s_cbranch, no divergence.
// LDS: K 34816 + V 36864 + 2 x P 9216 = 90112 -> 1 block/CU, 8 waves/CU
// (same SIMD occupancy as R0's two co-resident blocks).
#define KSTR 136    // K LDS row stride (bf16)
#define VSTR 72     // Vt LDS row stride: 64 tok + 8 pad
#define PSTR 72     // P LDS row stride: 64 keys + 8 pad
#define OSTR 260    // O combine stride (fp32 words)
#define K_OFF 0
#define V_OFF 34816
#define P_OFF 71680
#define PSZ  9216   // per-strip P region
#define SM_TOTAL 90112

__global__ __launch_bounds__(512, 1) void attn_kernel(
    const unsigned short* __restrict__ qg, const unsigned short* __restrict__ kg,
    const unsigned short* __restrict__ vg, const float* __restrict__ lam,
    float* __restrict__ outp) {
    __shared__ __align__(16) unsigned char smem[SM_TOTAL];
    unsigned short* Ks = (unsigned short*)(smem + K_OFF);  // [2][64][136] shared
    unsigned short* Vt = (unsigned short*)(smem + V_OFF);  // [256][72] shared

    const int t = threadIdx.x;
    const int id = blockIdx.x;             // 256 blocks
    const int b = id & 7;                  // batch -> XCD round-robin
    const int kp = id >> 3;                // 0..31 pair index

    const int w = t >> 6, lane = t & 63;
    const int l31 = lane & 31, lh = lane >> 5;
    const int sg = w >> 2;                 // strip slot: 0=heavy, 1=light
    const int term = w & 1;
    const int kh = (w >> 1) & 1;           // QK k-half / PV d-half

    const int strip = sg ? kp : (63 - kp);
    const int q0 = strip * 32;
    const int ntS = (strip >> 1) + 1;      // this strip's 64-key tiles
    const int ntB = ((63 - kp) >> 1) + 1;  // block tiles (heavy strip)

    unsigned short* Ps = (unsigned short*)(smem + P_OFF + sg * PSZ); // [2][32][72]
    float* Lsum = (float*)(smem + P_OFF + sg * PSZ);   // overlays dead Ps
    float* Ol = (float*)(smem + sg * V_OFF);           // sg0->K region, sg1->V region

    const float cn = lam[term];            // lam[1] carries the minus sign

    // Q A-frags (32x32x16 layout: row=lane&31, k=lh*8+j), 8 k-steps in registers
    const unsigned short* qrow = qg
        + ((size_t)(term * B_DIM + b) * T_DIM + q0 + l31) * HS_DIM + lh * 8;
    s8v qa[8];
    #pragma unroll
    for (int ks = 0; ks < 8; ++ks)
        qa[ks] = *(const s8v*)(qrow + ks * 16);

    f32x16 o[4];
    #pragma unroll
    for (int dt = 0; dt < 4; ++dt)
        #pragma unroll
        for (int r = 0; r < 16; ++r) o[dt][r] = 0.f;
    float l_acc[16];
    #pragma unroll
    for (int r = 0; r < 16; ++r) l_acc[r] = 0.f;

    for (int it = 0; it < ntB; ++it) {
        const int s0 = it * 64;
        // ---- stage K (2 terms x 64 keys x 128), all 512 threads ----
        #pragma unroll
        for (int rep = 0; rep < 4; ++rep) {
            int idx = t + rep * 512;       // 0..2047 uint4s
            int n = idx >> 10, rem = idx & 1023;
            int r = rem >> 4, seg = rem & 15;
            const uint4 g = *(const uint4*)(kg
                + ((size_t)(n * B_DIM + b) * T_DIM + s0 + r) * HS_DIM + seg * 8);
            *(uint4*)&Ks[(n * 64 + r) * KSTR + seg * 8] = g;
        }
        // ---- stage Vt (256 dims x 64 tokens), all 512 threads ----
        #pragma unroll
        for (int rep = 0; rep < 4; ++rep) {
            int idx = t + rep * 512;       // 0..2047 uint4s
            int d = idx >> 3, seg = idx & 7;
            const uint4 g = *(const uint4*)(vg
                + ((size_t)(b * VD + d) * T_DIM + s0) + seg * 8);
            *(uint4*)&Vt[d * VSTR + seg * 8] = g;
        }
        __syncthreads();

        if (it < ntS) {                    // wave-uniform strip participation
            // ---- QK: S[32q x 32k] for (sg, term, khalf) ----
            f32x16 sc;
            #pragma unroll
            for (int r = 0; r < 16; ++r) sc[r] = 0.f;
            #pragma unroll
            for (int ks = 0; ks < 8; ++ks) {
                s8v kf = *(const s8v*)&Ks[(term * 64 + kh * 32 + l31) * KSTR
                                          + ks * 16 + lh * 8];
                sc = __builtin_amdgcn_mfma_f32_32x32x16_bf16(qa[ks], kf, sc, 0, 0, 0);
            }
            // exp + P write (C/D 32x32: col=l31, row=(r&3)+8*(r>>2)+4*lh)
            const int key = s0 + kh * 32 + l31;
            #pragma unroll
            for (int r = 0; r < 16; ++r) {
                const int row = (r & 3) + 8 * (r >> 2) + 4 * lh;
                const float p = (key <= q0 + row) ? __expf(sc[r] * SCALE) : 0.f;
                l_acc[r] += p;
                Ps[(term * 32 + row) * PSTR + kh * 32 + l31] = (unsigned short)bf16_rne(p);
            }
        }
        __syncthreads();

        if (it < ntS) {
            // ---- PV: O[32q x 128d] += P[32x64] @ V[64x128] for (term, dhalf) ----
            #pragma unroll
            for (int ks = 0; ks < 4; ++ks) {
                s8v pa = *(const s8v*)&Ps[(term * 32 + l31) * PSTR + ks * 16 + lh * 8];
                #pragma unroll
                for (int dt = 0; dt < 4; ++dt) {
                    s8v vb = *(const s8v*)&Vt[(kh * 128 + dt * 32 + l31) * VSTR
                                              + ks * 16 + lh * 8];
                    o[dt] = __builtin_amdgcn_mfma_f32_32x32x16_bf16(pa, vb, o[dt], 0, 0, 0);
                }
            }
        }
        __syncthreads();
    }

    // ---- finalize l per strip: intra-wave reduce, combine kh partials ----
    #pragma unroll
    for (int r = 0; r < 16; ++r) {
        float lt = l_acc[r];
        #pragma unroll
        for (int off = 1; off < 32; off <<= 1) lt += __shfl_xor(lt, off);
        if (l31 == 0) {
            const int row = (r & 3) + 8 * (r >> 2) + 4 * lh;
            Lsum[(term * 2 + kh) * 32 + row] = lt;
        }
    }
    __syncthreads();
    float inv[16];
    #pragma unroll
    for (int r = 0; r < 16; ++r) {
        const int row = (r & 3) + 8 * (r >> 2) + 4 * lh;
        inv[r] = cn / (Lsum[(term * 2 + 0) * 32 + row] + Lsum[(term * 2 + 1) * 32 + row]);
    }

    // ---- combine terms via per-strip LDS overlay (sg0->K, sg1->V region) ----
    if (term) {
        #pragma unroll
        for (int dt = 0; dt < 4; ++dt)
            #pragma unroll
            for (int r = 0; r < 16; ++r) {
                const int row = (r & 3) + 8 * (r >> 2) + 4 * lh;
                Ol[row * OSTR + kh * 128 + dt * 32 + l31] = o[dt][r] * inv[r];
            }
    }
    __syncthreads();
    if (!term) {
        #pragma unroll
        for (int dt = 0; dt < 4; ++dt)
            #pragma unroll
            for (int r = 0; r < 16; ++r) {
                const int row = (r & 3) + 8 * (r >> 2) + 4 * lh;
                Ol[row * OSTR + kh * 128 + dt * 32 + l31] += o[dt][r] * inv[r];
            }
    }
    __syncthreads();
    // ---- store: each strip's 256 threads write its 32 rows ----
    #pragma unroll
    for (int rep = 0; rep < 8; ++rep) {
        int idx = (t & 255) + rep * 256;   // 32 rows x 64 float4
        int row = idx >> 6, c4 = idx & 63;
        float4 val = *(const float4*)&Ol[row * OSTR + c4 * 4];
        *(float4*)&outp[((size_t)(b * T_DIM + q0 + row)) * VD + c4 * 4] = val;
    }
}

extern "C" void kernel_launch(void* const* d_in, const int* in_sizes, int n_in,
                              void* d_out, int out_size, void* d_ws, size_t ws_size,
                              hipStream_t stream) {
    const float* x  = (const float*)d_in[0];
    const float* Wq = (const float*)d_in[1];
    const float* Wk = (const float*)d_in[2];
    const float* Wv = (const float*)d_in[3];
    const float* lq = (const float*)d_in[4];
    const float* lk = (const float*)d_in[5];
    const int* lidx = (const int*)d_in[6];

    unsigned short* ws = (unsigned short*)d_ws;
    unsigned short* qb   = ws + QB_OFF;    // [2][8][2048][128] bf16
    unsigned short* kb   = ws + KB_OFF;    // [2][8][2048][128] bf16
    unsigned short* vTb  = ws + VT_OFF;    // [8][256][2048] bf16
    unsigned short* wtb  = ws + WT_OFF;    // [768][1024] bf16
    unsigned short* xbhi = ws + XBH_OFF;   // x-bf16 rows 8192..16383
    float* lamb = (float*)(ws + LAM_OFF);
    unsigned short* xblo = (unsigned short*)d_out;  // scratch; attn overwrites d_out
    (void)ws_size; (void)in_sizes; (void)n_in; (void)out_size;

    lam_kernel<<<dim3(1), dim3(64), 0, stream>>>(lq, lk, lidx, lamb);
    cast_x_kernel<<<dim3(8192), dim3(256), 0, stream>>>(x, xblo, xbhi);
    cast_wt_kernel<<<dim3(24, 32), dim3(256), 0, stream>>>(Wq, Wk, Wv, wtb);
    gemm_kernel<<<dim3(128, 6), dim3(256), 0, stream>>>(xblo, xbhi, wtb, qb, kb, vTb);
    attn_kernel<<<dim3(256), dim3(512), 0, stream>>>(qb, kb, vTb, lamb, (float*)d_out);
}

// Round 9
// 213.746 us; speedup vs baseline: 1.0680x; 1.0680x over previous
//
#include <hip/hip_runtime.h>
#include <math.h>

// Problem constants
#define B_DIM 8
#define T_DIM 2048
#define C_DIM 1024
#define HS_DIM 128
#define VD 256
#define M_DIM (B_DIM * T_DIM)            // 16384 rows
#define QK_ELEMS (M_DIM * HS_DIM)        // 2,097,152 elems per (q|k) term
#define SCALE 0.088388347648318447f      // 1/sqrt(128)
#define LOG_THETA 9.210340371976184f     // ln(10000)

// workspace layout (ushort units)
#define QB_OFF   0u
#define KB_OFF   4194304u
#define VT_OFF   8388608u
#define WT_OFF   12582912u
#define XBH_OFF  13369344u               // x-bf16 rows 8192..16383
#define LAM_OFF  21757952u
#define XSPLIT_ELEMS 8388608u            // rows 0..8191 of x-bf16 live in d_out

typedef short s8v   __attribute__((ext_vector_type(8)));   // 8 bf16 (4 VGPRs)
typedef float f32x4 __attribute__((ext_vector_type(4)));
typedef float f32x16 __attribute__((ext_vector_type(16)));

// ---------- helpers ----------
__device__ __forceinline__ unsigned int bf16_rne(float f) {
    unsigned int u = __float_as_uint(f);
    return (u + 0x7fffu + ((u >> 16) & 1u)) >> 16;
}
__device__ __forceinline__ unsigned int pack_bf2(float lo, float hi) {
    return bf16_rne(lo) | (bf16_rne(hi) << 16);
}
__device__ __forceinline__ void async_cp16(const unsigned short* g, unsigned short* l) {
    __builtin_amdgcn_global_load_lds(
        (const __attribute__((address_space(1))) unsigned int*)g,
        (__attribute__((address_space(3))) unsigned int*)l, 16, 0, 0);
}

// ---------- kernel 1: lambda coefficients ----------
__global__ void lam_kernel(const float* __restrict__ lq, const float* __restrict__ lk,
                           const int* __restrict__ lidx, float* __restrict__ lam_out) {
    int t = threadIdx.x; // 64 threads = 1 wave
    float s0 = expf(lq[t] * lk[t]) + expf(lq[t + 64] * lk[t + 64]);
    float s1 = expf(lq[128 + t] * lk[128 + t]) + expf(lq[192 + t] * lk[192 + t]);
    #pragma unroll
    for (int off = 32; off > 0; off >>= 1) {
        s0 += __shfl_down(s0, off);
        s1 += __shfl_down(s1, off);
    }
    if (t == 0) {
        float e0 = s0 * (1.0f / 128.0f);
        float e1 = s1 * (1.0f / 128.0f);
        float li = 0.8f - 0.6f * expf(-0.3f * ((float)lidx[0] - 1.0f));
        lam_out[0] = e0 + li;            // +lam0
        lam_out[1] = -(e1 - e0 + li);    // -lam1
    }
}

// ---------- kernel 2a: cast x -> bf16 (split across d_out scratch + ws) ----------
__global__ __launch_bounds__(256) void cast_x_kernel(const float* __restrict__ x,
                                                     unsigned short* __restrict__ lo,
                                                     unsigned short* __restrict__ hi) {
    const size_t i8 = ((size_t)blockIdx.x * 256 + threadIdx.x) * 8;
    float4 a = *(const float4*)(x + i8);
    float4 b = *(const float4*)(x + i8 + 4);
    uint4 u;
    u.x = pack_bf2(a.x, a.y); u.y = pack_bf2(a.z, a.w);
    u.z = pack_bf2(b.x, b.y); u.w = pack_bf2(b.z, b.w);
    unsigned short* dst = (i8 < XSPLIT_ELEMS) ? (lo + i8) : (hi + (i8 - XSPLIT_ELEMS));
    *(uint4*)dst = u;
}

// ---------- kernel 2b: build Wt[768][1024] bf16 (transposed, concatenated) ----
// Q/K segments (seg 0..3) store PERMUTED columns: position n holds source dim
// pi(n) = 2*((n&15)+((n>>5)<<4)) + ((n>>4)&1)  (bijection per 128-col segment).
// This puts each RoPE rotation pair (2m,2m+1) into ONE lane's (j,j+1) MFMA
// register pair in the gemm epilogue -> RoPE with zero cross-lane shfl.
// V segments (seg 4..5) unpermuted.
__global__ __launch_bounds__(256) void cast_wt_kernel(
    const float* __restrict__ Wq, const float* __restrict__ Wk,
    const float* __restrict__ Wv, unsigned short* __restrict__ wt) {
    __shared__ float tile[32][33];
    const int t = threadIdx.x;
    const int n0 = blockIdx.x * 32;
    const int k0 = blockIdx.y * 32;
    const int seg = n0 >> 7;
    const int nl = t & 31;
    const int ng = n0 + nl;
    const int ngl = ng & 127;
    const int pcol = 2 * ((ngl & 15) + ((ngl >> 5) << 4)) + ((ngl >> 4) & 1);
    const float* src; int ld;
    if (seg < 2)      { src = Wq + (size_t)seg * (C_DIM * HS_DIM) + pcol; ld = 128; }
    else if (seg < 4) { src = Wk + (size_t)(seg - 2) * (C_DIM * HS_DIM) + pcol; ld = 128; }
    else              { src = Wv + (ng - 512); ld = 256; }
    #pragma unroll
    for (int rep = 0; rep < 4; ++rep) {
        int kl = (t >> 5) + rep * 8;
        tile[kl][nl] = src[(size_t)(k0 + kl) * ld];
    }
    __syncthreads();
    unsigned int* wt32 = (unsigned int*)wt;
    #pragma unroll
    for (int rep = 0; rep < 2; ++rep) {
        int nl2 = (t >> 4) + rep * 16;
        int k2 = (t & 15) * 2;
        unsigned int u = pack_bf2(tile[k2][nl2], tile[k2 + 1][nl2]);
        wt32[((size_t)(n0 + nl2) * 1024 + k0 + k2) >> 1] = u;
    }
}

// ---------- kernel 2c: bf16 MFMA GEMM + RoPE / V-transpose epilogue ----------
__global__ __launch_bounds__(256) void gemm_kernel(
    const unsigned short* __restrict__ xlo, const unsigned short* __restrict__ xhi,
    const unsigned short* __restrict__ wt,
    unsigned short* __restrict__ qo, unsigned short* __restrict__ ko,
    unsigned short* __restrict__ vo) {
    __shared__ unsigned short As[128 * 32];   // 8 KB, row-major [128][32]
    __shared__ unsigned short Bs[128 * 32];   // 8 KB, row-major [128][32]

    const int t = threadIdx.x;
    const int wv = t >> 6, lane = t & 63;
    const int quad = lane >> 4, l15 = lane & 15;
    const int m0 = blockIdx.x * 128;
    const int n0 = blockIdx.y * 128;
    const int wr = wv >> 1, wc = wv & 1;

    const unsigned short* xbase = (m0 < 8192)
        ? (xlo + (size_t)m0 * C_DIM) : (xhi + (size_t)(m0 - 8192) * C_DIM);

    f32x4 acc[4][4];
    #pragma unroll
    for (int i = 0; i < 4; ++i)
        #pragma unroll
        for (int j = 0; j < 4; ++j) acc[i][j] = (f32x4){0.f, 0.f, 0.f, 0.f};

    const int srow = lane >> 2;
    const int skof = (lane & 3) * 8;

    for (int k0 = 0; k0 < C_DIM; k0 += 32) {
        #pragma unroll
        for (int j = 0; j < 2; ++j) {
            const int c = wv * 2 + j;
            async_cp16(xbase + (size_t)(c * 16 + srow) * C_DIM + k0 + skof, As + c * 512);
        }
        #pragma unroll
        for (int j = 0; j < 2; ++j) {
            const int c = wv * 2 + j;
            async_cp16(wt + (size_t)(n0 + c * 16 + srow) * C_DIM + k0 + skof, Bs + c * 512);
        }
        __syncthreads();
        s8v af[4], bf[4];
        #pragma unroll
        for (int i = 0; i < 4; ++i)
            af[i] = *(const s8v*)&As[(wr * 64 + i * 16 + l15) * 32 + quad * 8];
        #pragma unroll
        for (int j = 0; j < 4; ++j)
            bf[j] = *(const s8v*)&Bs[(wc * 64 + j * 16 + l15) * 32 + quad * 8];
        #pragma unroll
        for (int i = 0; i < 4; ++i)
            #pragma unroll
            for (int j = 0; j < 4; ++j)
                acc[i][j] = __builtin_amdgcn_mfma_f32_16x16x32_bf16(af[i], bf[j], acc[i][j], 0, 0, 0);
        __syncthreads();
    }

    const int seg = n0 >> 7;   // 0..5
    if (seg < 4) {
        unsigned short* dstbuf = ((seg < 2) ? qo : ko) + (size_t)(seg & 1) * QK_ELEMS;
        // pair-index (= d>>1) for j-pairs (0,1) and (2,3)
        const int mi0 = l15 + 32 * wc;
        const int mi1 = mi0 + 16;
        const float freq0 = __expf((float)mi0 * (-LOG_THETA / 64.f));
        const float freq1 = __expf((float)mi1 * (-LOG_THETA / 64.f));
        #pragma unroll
        for (int i = 0; i < 4; ++i) {
            #pragma unroll
            for (int e = 0; e < 4; ++e) {
                const int m = m0 + wr * 64 + i * 16 + quad * 4 + e;
                const float trow = (float)(m & (T_DIM - 1));
                unsigned int* p32 = (unsigned int*)(dstbuf + (size_t)m * HS_DIM);
                float sn0, cs0, sn1, cs1;
                __sincosf(trow * freq0, &sn0, &cs0);
                __sincosf(trow * freq1, &sn1, &cs1);
                const float xr0 = acc[i][0][e], xi0 = acc[i][1][e];
                const float xr1 = acc[i][2][e], xi1 = acc[i][3][e];
                p32[mi0] = pack_bf2(xr0 * cs0 - xi0 * sn0, xr0 * sn0 + xi0 * cs0);
                p32[mi1] = pack_bf2(xr1 * cs1 - xi1 * sn1, xr1 * sn1 + xi1 * cs1);
            }
        }
    } else {
        const int bq = m0 >> 11;
        const int tbase = m0 & (T_DIM - 1);
        unsigned int* vT32 = (unsigned int*)vo;
        #pragma unroll
        for (int j = 0; j < 4; ++j) {
            const int d = (seg - 4) * 128 + wc * 64 + j * 16 + l15;
            const size_t rowbase = (size_t)(bq * VD + d) * (T_DIM / 2); // u32 units
            #pragma unroll
            for (int i = 0; i < 4; ++i) {
                const int tok = tbase + wr * 64 + i * 16 + quad * 4;
                uint2 u;
                u.x = pack_bf2(acc[i][j][0], acc[i][j][1]);
                u.y = pack_bf2(acc[i][j][2], acc[i][j][3]);
                *(uint2*)&vT32[rowbase + (tok >> 1)] = u;
            }
        }
    }
}

// ---------- kernel 3: dual-term causal attention, 32x32 bf16 MFMA ----------
// Round-9: glds double-buffered pipeline on the 8-wave merged block.
// Evidence chain: R8 halved staged bytes -> ZERO change (5715 cyc/tile
// invariant) => the cost is register-BATCHED load latency serialized between
// barriers, not bandwidth. Fix: stage via global_load_lds (no registers, no
// batching), double-buffer K/V, and defer the ONLY vmcnt(0) drain to the
// end-of-tile __syncthreads -- a full tile of compute covers it. Mid barrier
// is a single inline-asm {lgkmcnt(0); s_barrier} that does NOT drain vmcnt
// (the flaw in R0/R8's __syncthreads). 2 barriers/tile.
// LDS layout (glds requires linear rows): K rows 256B, V drow-paired rows
// 256B, 16-slot XOR swizzle slot^(row&15) applied on the SOURCE address at
// staging and on the READ address (both-sides rule). ~2-4-way conflicts
// accepted (~300 cyc/tile) vs ~3000+ cyc of load serialization removed.
// LDS: 2 x 65536 (K 32768 + V 32768) + 2 x 9216 P = 149504 -> 1 block/CU,
// 8 waves (2/SIMD, same as R8).
#define PSTR 72      // P LDS row stride: 64 keys + 8 pad
#define OSTR 260     // O combine stride (fp32 words)
#define BUFB 65536   // bytes per K+V buffer
#define P_OFF 131072
#define PSZ  9216    // per-strip P region
#define SM_TOTAL 149504

__global__ __launch_bounds__(512, 1) void attn_kernel(
    const unsigned short* __restrict__ qg, const unsigned short* __restrict__ kg,
    const unsigned short* __restrict__ vg, const float* __restrict__ lam,
    float* __restrict__ outp) {
    __shared__ __align__(16) unsigned char smem[SM_TOTAL];

    const int t = threadIdx.x;
    const int id = blockIdx.x;             // 256 blocks
    const int b = id & 7;                  // batch -> XCD round-robin
    const int kp = id >> 3;                // 0..31 pair index

    const int w = t >> 6, lane = t & 63;
    const int l31 = lane & 31, lh = lane >> 5;
    const int sg = w >> 2;                 // strip slot: 0=heavy, 1=light
    const int term = w & 1;
    const int kh = (w >> 1) & 1;           // QK k-half / PV d-half

    const int strip = sg ? kp : (63 - kp);
    const int q0 = strip * 32;
    const int ntS = (strip >> 1) + 1;      // this strip's 64-key tiles
    const int ntB = ((63 - kp) >> 1) + 1;  // block tiles (heavy strip)

    unsigned short* Ps = (unsigned short*)(smem + P_OFF + sg * PSZ); // [2][32][72]
    float* Lsum = (float*)(smem + P_OFF + sg * PSZ);   // overlays dead Ps
    float* Ol = (float*)(smem + sg * BUFB);            // sg0->buf0, sg1->buf1

    const float cn = lam[term];            // lam[1] carries the minus sign

    // Q A-frags (32x32x16 layout: row=lane&31, k=lh*8+j), 8 k-steps in registers
    const unsigned short* qrow = qg
        + ((size_t)(term * B_DIM + b) * T_DIM + q0 + l31) * HS_DIM + lh * 8;
    s8v qa[8];
    #pragma unroll
    for (int ks = 0; ks < 8; ++ks)
        qa[ks] = *(const s8v*)(qrow + ks * 16);

    // ---- glds staging geometry (chunk c = t + rep*512, c in 0..2047) ----
    // K: rowg=c>>4 (kterm=rowg>>6, krow=rowg&63), slot=c&15,
    //    srcslot = slot^(krow&15); LDS linear at c*16 within K region.
    // V: drow=c>>4 (dim pair), slot=c&15, srcslot=slot^(drow&15),
    //    dim=2*drow+(srcslot>>3), tokc=srcslot&7; LDS linear at c*16 in V.
    unsigned int kOffA[4], vOffA[4];
    #pragma unroll
    for (int rep = 0; rep < 4; ++rep) {
        const int c = t + rep * 512;
        const int rowg = c >> 4, slot = c & 15;
        const int kterm = rowg >> 6, krow = rowg & 63;
        const int kss = slot ^ (krow & 15);
        kOffA[rep] = (unsigned int)(((kterm * B_DIM + b) * T_DIM + krow) * HS_DIM
                                    + kss * 8);
        const int drow = rowg;
        const int vss = slot ^ (drow & 15);
        const int dim = 2 * drow + (vss >> 3), tokc = vss & 7;
        vOffA[rep] = (unsigned int)((b * VD + dim) * T_DIM + tokc * 8);
    }

    f32x16 o[4];
    #pragma unroll
    for (int dt = 0; dt < 4; ++dt)
        #pragma unroll
        for (int r = 0; r < 16; ++r) o[dt][r] = 0.f;
    float l_acc[16];
    #pragma unroll
    for (int r = 0; r < 16; ++r) l_acc[r] = 0.f;

    // ---- prologue: stage tile 0 into buf 0 (drain at first __syncthreads) --
    {
        unsigned short* kb0 = (unsigned short*)(smem + w * 1024);
        unsigned short* vb0 = (unsigned short*)(smem + 32768 + w * 1024);
        #pragma unroll
        for (int rep = 0; rep < 4; ++rep) {
            async_cp16(kg + kOffA[rep], kb0 + rep * 4096);
            async_cp16(vg + vOffA[rep], vb0 + rep * 4096);
        }
    }
    __syncthreads();

    const int krow = kh * 32 + l31;        // QK K row for this lane
    const int k15 = l31 & 15;

    for (int it = 0; it < ntB; ++it) {
        const int s0 = it * 64;
        const unsigned char* buf = smem + (it & 1) * BUFB;

        // ---- issue next tile's 8 glds (zero regs); drains only at the
        //      END-of-iter __syncthreads => full-tile latency cover ----
        if (it + 1 < ntB) {
            const int sn = s0 + 64;
            unsigned char* nbuf = smem + ((it + 1) & 1) * BUFB;
            unsigned short* kbn = (unsigned short*)(nbuf + w * 1024);
            unsigned short* vbn = (unsigned short*)(nbuf + 32768 + w * 1024);
            #pragma unroll
            for (int rep = 0; rep < 4; ++rep) {
                async_cp16(kg + kOffA[rep] + (size_t)sn * HS_DIM, kbn + rep * 4096);
                async_cp16(vg + vOffA[rep] + sn, vbn + rep * 4096);
            }
        }

        if (it < ntS) {                    // wave-uniform strip participation
            // ---- QK: S[32q x 32k], K rows 256B linear, 16-slot XOR reads ----
            const unsigned short* Kb = (const unsigned short*)buf;
            f32x16 sc;
            #pragma unroll
            for (int r = 0; r < 16; ++r) sc[r] = 0.f;
            __builtin_amdgcn_s_setprio(1);
            #pragma unroll
            for (int ks = 0; ks < 8; ++ks) {
                const int x = (ks * 2 + lh) ^ k15;
                s8v kf = *(const s8v*)&Kb[(term * 64 + krow) * 128 + x * 8];
                sc = __builtin_amdgcn_mfma_f32_32x32x16_bf16(qa[ks], kf, sc, 0, 0, 0);
            }
            __builtin_amdgcn_s_setprio(0);
            // exp + P write (C/D 32x32: col=l31, row=(r&3)+8*(r>>2)+4*lh)
            const int key = s0 + kh * 32 + l31;
            #pragma unroll
            for (int r = 0; r < 16; ++r) {
                const int row = (r & 3) + 8 * (r >> 2) + 4 * lh;
                const float p = (key <= q0 + row) ? __expf(sc[r] * SCALE) : 0.f;
                l_acc[r] += p;
                Ps[(term * 32 + row) * PSTR + kh * 32 + l31] = (unsigned short)bf16_rne(p);
            }
        }
        // mid barrier: publish P; do NOT drain vmcnt (glds stays in flight)
        asm volatile("s_waitcnt lgkmcnt(0)\n\ts_barrier" ::: "memory");
        __builtin_amdgcn_sched_barrier(0);

        if (it < ntS) {
            // ---- PV: O[32q x 128d] += P[32x64] @ V[64x128] for (term, dh) ----
            const unsigned short* Vb = (const unsigned short*)(buf + 32768);
            __builtin_amdgcn_s_setprio(1);
            #pragma unroll
            for (int ks = 0; ks < 4; ++ks) {
                s8v pa = *(const s8v*)&Ps[(term * 32 + l31) * PSTR + ks * 16 + lh * 8];
                #pragma unroll
                for (int dt = 0; dt < 4; ++dt) {
                    const int dim = kh * 128 + dt * 32 + l31;
                    const int drow = dim >> 1;
                    const int x = ((dim & 1) * 8 + ks * 2 + lh) ^ (drow & 15);
                    s8v vb = *(const s8v*)&Vb[(drow * 16 + x) * 8];
                    o[dt] = __builtin_amdgcn_mfma_f32_32x32x16_bf16(pa, vb, o[dt], 0, 0, 0);
                }
            }
            __builtin_amdgcn_s_setprio(0);
        }
        // end barrier: drains vmcnt(0) (covered by the whole tile) + lgkm;
        // next iter's QK may read the freshly staged buffer, P is free.
        __syncthreads();
    }

    // ---- finalize l per strip: intra-wave reduce, combine kh partials ----
    #pragma unroll
    for (int r = 0; r < 16; ++r) {
        float lt = l_acc[r];
        #pragma unroll
        for (int off = 1; off < 32; off <<= 1) lt += __shfl_xor(lt, off);
        if (l31 == 0) {
            const int row = (r & 3) + 8 * (r >> 2) + 4 * lh;
            Lsum[(term * 2 + kh) * 32 + row] = lt;
        }
    }
    __syncthreads();
    float inv[16];
    #pragma unroll
    for (int r = 0; r < 16; ++r) {
        const int row = (r & 3) + 8 * (r >> 2) + 4 * lh;
        inv[r] = cn / (Lsum[(term * 2 + 0) * 32 + row] + Lsum[(term * 2 + 1) * 32 + row]);
    }

    // ---- combine terms via per-strip LDS overlay (sg0->buf0, sg1->buf1) ----
    if (term) {
        #pragma unroll
        for (int dt = 0; dt < 4; ++dt)
            #pragma unroll
            for (int r = 0; r < 16; ++r) {
                const int row = (r & 3) + 8 * (r >> 2) + 4 * lh;
                Ol[row * OSTR + kh * 128 + dt * 32 + l31] = o[dt][r] * inv[r];
            }
    }
    __syncthreads();
    if (!term) {
        #pragma unroll
        for (int dt = 0; dt < 4; ++dt)
            #pragma unroll
            for (int r = 0; r < 16; ++r) {
                const int row = (r & 3) + 8 * (r >> 2) + 4 * lh;
                Ol[row * OSTR + kh * 128 + dt * 32 + l31] += o[dt][r] * inv[r];
            }
    }
    __syncthreads();
    // ---- store: each strip's 256 threads write its 32 rows ----
    #pragma unroll
    for (int rep = 0; rep < 8; ++rep) {
        int idx = (t & 255) + rep * 256;   // 32 rows x 64 float4
        int row = idx >> 6, c4 = idx & 63;
        float4 val = *(const float4*)&Ol[row * OSTR + c4 * 4];
        *(float4*)&outp[((size_t)(b * T_DIM + q0 + row)) * VD + c4 * 4] = val;
    }
}

extern "C" void kernel_launch(void* const* d_in, const int* in_sizes, int n_in,
                              void* d_out, int out_size, void* d_ws, size_t ws_size,
                              hipStream_t stream) {
    const float* x  = (const float*)d_in[0];
    const float* Wq = (const float*)d_in[1];
    const float* Wk = (const float*)d_in[2];
    const float* Wv = (const float*)d_in[3];
    const float* lq = (const float*)d_in[4];
    const float* lk = (const float*)d_in[5];
    const int* lidx = (const int*)d_in[6];

    unsigned short* ws = (unsigned short*)d_ws;
    unsigned short* qb   = ws + QB_OFF;    // [2][8][2048][128] bf16
    unsigned short* kb   = ws + KB_OFF;    // [2][8][2048][128] bf16
    unsigned short* vTb  = ws + VT_OFF;    // [8][256][2048] bf16
    unsigned short* wtb  = ws + WT_OFF;    // [768][1024] bf16
    unsigned short* xbhi = ws + XBH_OFF;   // x-bf16 rows 8192..16383
    float* lamb = (float*)(ws + LAM_OFF);
    unsigned short* xblo = (unsigned short*)d_out;  // scratch; attn overwrites d_out
    (void)ws_size; (void)in_sizes; (void)n_in; (void)out_size;

    lam_kernel<<<dim3(1), dim3(64), 0, stream>>>(lq, lk, lidx, lamb);
    cast_x_kernel<<<dim3(8192), dim3(256), 0, stream>>>(x, xblo, xbhi);
    cast_wt_kernel<<<dim3(24, 32), dim3(256), 0, stream>>>(Wq, Wk, Wv, wtb);
    gemm_kernel<<<dim3(128, 6), dim3(256), 0, stream>>>(xblo, xbhi, wtb, qb, kb, vTb);
    attn_kernel<<<dim3(256), dim3(512), 0, stream>>>(qb, kb, vTb, lamb, (float*)d_out);
}

// Round 10
// 204.770 us; speedup vs baseline: 1.1148x; 1.0438x over previous
//
#include <hip/hip_runtime.h>
#include <math.h>

// Problem constants
#define B_DIM 8
#define T_DIM 2048
#define C_DIM 1024
#define HS_DIM 128
#define VD 256
#define M_DIM (B_DIM * T_DIM)            // 16384 rows
#define QK_ELEMS (M_DIM * HS_DIM)        // 2,097,152 elems per (q|k) term
#define SCALE 0.088388347648318447f      // 1/sqrt(128)
#define LOG_THETA 9.210340371976184f     // ln(10000)

// workspace layout (ushort units)
#define QB_OFF   0u
#define KB_OFF   4194304u
#define VT_OFF   8388608u
#define WT_OFF   12582912u
#define XBH_OFF  13369344u               // x-bf16 rows 8192..16383
#define LAM_OFF  21757952u
#define XSPLIT_ELEMS 8388608u            // rows 0..8191 of x-bf16 live in d_out

typedef short s8v   __attribute__((ext_vector_type(8)));   // 8 bf16 (4 VGPRs)
typedef float f32x4 __attribute__((ext_vector_type(4)));
typedef float f32x16 __attribute__((ext_vector_type(16)));

// ---------- helpers ----------
__device__ __forceinline__ unsigned int bf16_rne(float f) {
    unsigned int u = __float_as_uint(f);
    return (u + 0x7fffu + ((u >> 16) & 1u)) >> 16;
}
__device__ __forceinline__ unsigned int pack_bf2(float lo, float hi) {
    return bf16_rne(lo) | (bf16_rne(hi) << 16);
}
__device__ __forceinline__ void async_cp16(const unsigned short* g, unsigned short* l) {
    __builtin_amdgcn_global_load_lds(
        (const __attribute__((address_space(1))) unsigned int*)g,
        (__attribute__((address_space(3))) unsigned int*)l, 16, 0, 0);
}

// ---------- kernel 1: fused prep (cast_x | cast_wt | lam), one dispatch ----
// blockIdx < 8192:  cast x -> bf16 (split across d_out scratch + ws)
// blockIdx < 8960:  build Wt[768][1024] bf16 (transposed, RoPE-permuted Q/K)
// blockIdx == 8960: lambda coefficients (1 wave)
__global__ __launch_bounds__(256) void prep_kernel(
    const float* __restrict__ x,
    const float* __restrict__ Wq, const float* __restrict__ Wk,
    const float* __restrict__ Wv,
    const float* __restrict__ lq, const float* __restrict__ lk,
    const int* __restrict__ lidx,
    unsigned short* __restrict__ xlo, unsigned short* __restrict__ xhi,
    unsigned short* __restrict__ wt, float* __restrict__ lam_out) {
    __shared__ float tile[32][33];
    const int bx = blockIdx.x;
    const int t = threadIdx.x;

    if (bx < 8192) {
        // ---- cast_x ----
        const size_t i8 = ((size_t)bx * 256 + t) * 8;
        float4 a = *(const float4*)(x + i8);
        float4 b = *(const float4*)(x + i8 + 4);
        uint4 u;
        u.x = pack_bf2(a.x, a.y); u.y = pack_bf2(a.z, a.w);
        u.z = pack_bf2(b.x, b.y); u.w = pack_bf2(b.z, b.w);
        unsigned short* dst = (i8 < XSPLIT_ELEMS) ? (xlo + i8) : (xhi + (i8 - XSPLIT_ELEMS));
        *(uint4*)dst = u;
    } else if (bx < 8960) {
        // ---- cast_wt: Q/K columns RoPE-permuted:
        // pi(n) = 2*((n&15)+((n>>5)<<4)) + ((n>>4)&1) per 128-col segment ----
        const int bxx = bx - 8192;
        const int n0 = (bxx % 24) * 32;
        const int k0 = (bxx / 24) * 32;
        const int seg = n0 >> 7;
        const int nl = t & 31;
        const int ng = n0 + nl;
        const int ngl = ng & 127;
        const int pcol = 2 * ((ngl & 15) + ((ngl >> 5) << 4)) + ((ngl >> 4) & 1);
        const float* src; int ld;
        if (seg < 2)      { src = Wq + (size_t)seg * (C_DIM * HS_DIM) + pcol; ld = 128; }
        else if (seg < 4) { src = Wk + (size_t)(seg - 2) * (C_DIM * HS_DIM) + pcol; ld = 128; }
        else              { src = Wv + (ng - 512); ld = 256; }
        #pragma unroll
        for (int rep = 0; rep < 4; ++rep) {
            int kl = (t >> 5) + rep * 8;
            tile[kl][nl] = src[(size_t)(k0 + kl) * ld];
        }
        __syncthreads();
        unsigned int* wt32 = (unsigned int*)wt;
        #pragma unroll
        for (int rep = 0; rep < 2; ++rep) {
            int nl2 = (t >> 4) + rep * 16;
            int k2 = (t & 15) * 2;
            unsigned int u = pack_bf2(tile[k2][nl2], tile[k2 + 1][nl2]);
            wt32[((size_t)(n0 + nl2) * 1024 + k0 + k2) >> 1] = u;
        }
    } else {
        // ---- lam (1 wave) ----
        if (t < 64) {
            float s0 = expf(lq[t] * lk[t]) + expf(lq[t + 64] * lk[t + 64]);
            float s1 = expf(lq[128 + t] * lk[128 + t]) + expf(lq[192 + t] * lk[192 + t]);
            #pragma unroll
            for (int off = 32; off > 0; off >>= 1) {
                s0 += __shfl_down(s0, off);
                s1 += __shfl_down(s1, off);
            }
            if (t == 0) {
                float e0 = s0 * (1.0f / 128.0f);
                float e1 = s1 * (1.0f / 128.0f);
                float li = 0.8f - 0.6f * expf(-0.3f * ((float)lidx[0] - 1.0f));
                lam_out[0] = e0 + li;            // +lam0
                lam_out[1] = -(e1 - e0 + li);    // -lam1
            }
        }
    }
}

// ---------- kernel 2: bf16 MFMA GEMM + RoPE / V-transpose epilogue ----------
// Round-10: BK=64 (16 k-iters instead of 32 -> half the barrier/vmcnt-drain
// pairs, the m97-ceiling mechanism) with T2 XOR swizzle: row stride is now
// 128B (16-way conflict if linear), so chunk x ^= (row&7) is applied on BOTH
// the glds SOURCE column and the ds_read chunk (both-sides rule; bank check:
// max 2-way aliasing = free). Epilogue (RoPE-permuted in-lane rotation, V
// transpose) unchanged from round 7/9.
__global__ __launch_bounds__(256) void gemm_kernel(
    const unsigned short* __restrict__ xlo, const unsigned short* __restrict__ xhi,
    const unsigned short* __restrict__ wt,
    unsigned short* __restrict__ qo, unsigned short* __restrict__ ko,
    unsigned short* __restrict__ vo) {
    __shared__ unsigned short As[128 * 64];   // 16 KB, row-major [128][64], swz
    __shared__ unsigned short Bs[128 * 64];   // 16 KB

    const int t = threadIdx.x;
    const int wv = t >> 6, lane = t & 63;
    const int quad = lane >> 4, l15 = lane & 15;
    const int m0 = blockIdx.x * 128;
    const int n0 = blockIdx.y * 128;
    const int wr = wv >> 1, wc = wv & 1;

    const unsigned short* xbase = (m0 < 8192)
        ? (xlo + (size_t)m0 * C_DIM) : (xhi + (size_t)(m0 - 8192) * C_DIM);

    f32x4 acc[4][4];
    #pragma unroll
    for (int i = 0; i < 4; ++i)
        #pragma unroll
        for (int j = 0; j < 4; ++j) acc[i][j] = (f32x4){0.f, 0.f, 0.f, 0.f};

    // staging geometry: chunk ci = t + rep*256 (0..1023), row=ci>>3, slot=ci&7;
    // source col = k0 + (slot^(row&7))*8 ; LDS dst linear at ci*8 ushorts
    // (wave-uniform base + lane*16B as glds requires).
    int srow[4], sco[4];
    #pragma unroll
    for (int rep = 0; rep < 4; ++rep) {
        const int ci = t + rep * 256;
        srow[rep] = ci >> 3;
        sco[rep] = ((ci & 7) ^ (srow[rep] & 7)) * 8;
    }

    for (int k0 = 0; k0 < C_DIM; k0 += 64) {
        #pragma unroll
        for (int rep = 0; rep < 4; ++rep) {
            const int ci = t + rep * 256;
            async_cp16(xbase + (size_t)srow[rep] * C_DIM + k0 + sco[rep], As + ci * 8);
            async_cp16(wt + (size_t)(n0 + srow[rep]) * C_DIM + k0 + sco[rep], Bs + ci * 8);
        }
        __syncthreads();
        #pragma unroll
        for (int kk = 0; kk < 2; ++kk) {
            s8v af[4], bf[4];
            #pragma unroll
            for (int i = 0; i < 4; ++i) {
                const int row = wr * 64 + i * 16 + l15;
                const int xch = (kk * 4 + quad) ^ (row & 7);
                af[i] = *(const s8v*)&As[row * 64 + xch * 8];
            }
            #pragma unroll
            for (int j = 0; j < 4; ++j) {
                const int row = wc * 64 + j * 16 + l15;
                const int xch = (kk * 4 + quad) ^ (row & 7);
                bf[j] = *(const s8v*)&Bs[row * 64 + xch * 8];
            }
            #pragma unroll
            for (int i = 0; i < 4; ++i)
                #pragma unroll
                for (int j = 0; j < 4; ++j)
                    acc[i][j] = __builtin_amdgcn_mfma_f32_16x16x32_bf16(af[i], bf[j], acc[i][j], 0, 0, 0);
        }
        __syncthreads();
    }

    const int seg = n0 >> 7;   // 0..5
    if (seg < 4) {
        unsigned short* dstbuf = ((seg < 2) ? qo : ko) + (size_t)(seg & 1) * QK_ELEMS;
        // pair-index (= d>>1) for j-pairs (0,1) and (2,3)
        const int mi0 = l15 + 32 * wc;
        const int mi1 = mi0 + 16;
        const float freq0 = __expf((float)mi0 * (-LOG_THETA / 64.f));
        const float freq1 = __expf((float)mi1 * (-LOG_THETA / 64.f));
        #pragma unroll
        for (int i = 0; i < 4; ++i) {
            #pragma unroll
            for (int e = 0; e < 4; ++e) {
                const int m = m0 + wr * 64 + i * 16 + quad * 4 + e;
                const float trow = (float)(m & (T_DIM - 1));
                unsigned int* p32 = (unsigned int*)(dstbuf + (size_t)m * HS_DIM);
                float sn0, cs0, sn1, cs1;
                __sincosf(trow * freq0, &sn0, &cs0);
                __sincosf(trow * freq1, &sn1, &cs1);
                const float xr0 = acc[i][0][e], xi0 = acc[i][1][e];
                const float xr1 = acc[i][2][e], xi1 = acc[i][3][e];
                p32[mi0] = pack_bf2(xr0 * cs0 - xi0 * sn0, xr0 * sn0 + xi0 * cs0);
                p32[mi1] = pack_bf2(xr1 * cs1 - xi1 * sn1, xr1 * sn1 + xi1 * cs1);
            }
        }
    } else {
        const int bq = m0 >> 11;
        const int tbase = m0 & (T_DIM - 1);
        unsigned int* vT32 = (unsigned int*)vo;
        #pragma unroll
        for (int j = 0; j < 4; ++j) {
            const int d = (seg - 4) * 128 + wc * 64 + j * 16 + l15;
            const size_t rowbase = (size_t)(bq * VD + d) * (T_DIM / 2); // u32 units
            #pragma unroll
            for (int i = 0; i < 4; ++i) {
                const int tok = tbase + wr * 64 + i * 16 + quad * 4;
                uint2 u;
                u.x = pack_bf2(acc[i][j][0], acc[i][j][1]);
                u.y = pack_bf2(acc[i][j][2], acc[i][j][3]);
                *(uint2*)&vT32[rowbase + (tok >> 1)] = u;
            }
        }
    }
}

// ---------- kernel 3: dual-term causal attention, 32x32 bf16 MFMA ----------
// Round-9 structure (verified 64.6 us): glds double-buffered pipeline on the
// 8-wave merged block; only vmcnt(0) drain is the end-of-tile __syncthreads
// (full tile of compute cover); mid barrier is lgkmcnt-only; 16-slot XOR
// swizzle src+read (measured 0 bank conflicts).
#define PSTR 72      // P LDS row stride: 64 keys + 8 pad
#define OSTR 260     // O combine stride (fp32 words)
#define BUFB 65536   // bytes per K+V buffer
#define P_OFF 131072
#define PSZ  9216    // per-strip P region
#define SM_TOTAL 149504

__global__ __launch_bounds__(512, 1) void attn_kernel(
    const unsigned short* __restrict__ qg, const unsigned short* __restrict__ kg,
    const unsigned short* __restrict__ vg, const float* __restrict__ lam,
    float* __restrict__ outp) {
    __shared__ __align__(16) unsigned char smem[SM_TOTAL];

    const int t = threadIdx.x;
    const int id = blockIdx.x;             // 256 blocks
    const int b = id & 7;                  // batch -> XCD round-robin
    const int kp = id >> 3;                // 0..31 pair index

    const int w = t >> 6, lane = t & 63;
    const int l31 = lane & 31, lh = lane >> 5;
    const int sg = w >> 2;                 // strip slot: 0=heavy, 1=light
    const int term = w & 1;
    const int kh = (w >> 1) & 1;           // QK k-half / PV d-half

    const int strip = sg ? kp : (63 - kp);
    const int q0 = strip * 32;
    const int ntS = (strip >> 1) + 1;      // this strip's 64-key tiles
    const int ntB = ((63 - kp) >> 1) + 1;  // block tiles (heavy strip)

    unsigned short* Ps = (unsigned short*)(smem + P_OFF + sg * PSZ); // [2][32][72]
    float* Lsum = (float*)(smem + P_OFF + sg * PSZ);   // overlays dead Ps
    float* Ol = (float*)(smem + sg * BUFB);            // sg0->buf0, sg1->buf1

    const float cn = lam[term];            // lam[1] carries the minus sign

    // Q A-frags (32x32x16 layout: row=lane&31, k=lh*8+j), 8 k-steps in registers
    const unsigned short* qrow = qg
        + ((size_t)(term * B_DIM + b) * T_DIM + q0 + l31) * HS_DIM + lh * 8;
    s8v qa[8];
    #pragma unroll
    for (int ks = 0; ks < 8; ++ks)
        qa[ks] = *(const s8v*)(qrow + ks * 16);

    // ---- glds staging geometry (chunk c = t + rep*512, c in 0..2047) ----
    unsigned int kOffA[4], vOffA[4];
    #pragma unroll
    for (int rep = 0; rep < 4; ++rep) {
        const int c = t + rep * 512;
        const int rowg = c >> 4, slot = c & 15;
        const int kterm = rowg >> 6, krow = rowg & 63;
        const int kss = slot ^ (krow & 15);
        kOffA[rep] = (unsigned int)(((kterm * B_DIM + b) * T_DIM + krow) * HS_DIM
                                    + kss * 8);
        const int drow = rowg;
        const int vss = slot ^ (drow & 15);
        const int dim = 2 * drow + (vss >> 3), tokc = vss & 7;
        vOffA[rep] = (unsigned int)((b * VD + dim) * T_DIM + tokc * 8);
    }

    f32x16 o[4];
    #pragma unroll
    for (int dt = 0; dt < 4; ++dt)
        #pragma unroll
        for (int r = 0; r < 16; ++r) o[dt][r] = 0.f;
    float l_acc[16];
    #pragma unroll
    for (int r = 0; r < 16; ++r) l_acc[r] = 0.f;

    // ---- prologue: stage tile 0 into buf 0 (drain at first __syncthreads) --
    {
        unsigned short* kb0 = (unsigned short*)(smem + w * 1024);
        unsigned short* vb0 = (unsigned short*)(smem + 32768 + w * 1024);
        #pragma unroll
        for (int rep = 0; rep < 4; ++rep) {
            async_cp16(kg + kOffA[rep], kb0 + rep * 4096);
            async_cp16(vg + vOffA[rep], vb0 + rep * 4096);
        }
    }
    __syncthreads();

    const int krow = kh * 32 + l31;        // QK K row for this lane
    const int k15 = l31 & 15;

    for (int it = 0; it < ntB; ++it) {
        const int s0 = it * 64;
        const unsigned char* buf = smem + (it & 1) * BUFB;

        // ---- issue next tile's 8 glds (zero regs); drains only at the
        //      END-of-iter __syncthreads => full-tile latency cover ----
        if (it + 1 < ntB) {
            const int sn = s0 + 64;
            unsigned char* nbuf = smem + ((it + 1) & 1) * BUFB;
            unsigned short* kbn = (unsigned short*)(nbuf + w * 1024);
            unsigned short* vbn = (unsigned short*)(nbuf + 32768 + w * 1024);
            #pragma unroll
            for (int rep = 0; rep < 4; ++rep) {
                async_cp16(kg + kOffA[rep] + (size_t)sn * HS_DIM, kbn + rep * 4096);
                async_cp16(vg + vOffA[rep] + sn, vbn + rep * 4096);
            }
        }

        if (it < ntS) {                    // wave-uniform strip participation
            // ---- QK: S[32q x 32k], K rows 256B linear, 16-slot XOR reads ----
            const unsigned short* Kb = (const unsigned short*)buf;
            f32x16 sc;
            #pragma unroll
            for (int r = 0; r < 16; ++r) sc[r] = 0.f;
            __builtin_amdgcn_s_setprio(1);
            #pragma unroll
            for (int ks = 0; ks < 8; ++ks) {
                const int x = (ks * 2 + lh) ^ k15;
                s8v kf = *(const s8v*)&Kb[(term * 64 + krow) * 128 + x * 8];
                sc = __builtin_amdgcn_mfma_f32_32x32x16_bf16(qa[ks], kf, sc, 0, 0, 0);
            }
            __builtin_amdgcn_s_setprio(0);
            // exp + P write (C/D 32x32: col=l31, row=(r&3)+8*(r>>2)+4*lh)
            const int key = s0 + kh * 32 + l31;
            #pragma unroll
            for (int r = 0; r < 16; ++r) {
                const int row = (r & 3) + 8 * (r >> 2) + 4 * lh;
                const float p = (key <= q0 + row) ? __expf(sc[r] * SCALE) : 0.f;
                l_acc[r] += p;
                Ps[(term * 32 + row) * PSTR + kh * 32 + l31] = (unsigned short)bf16_rne(p);
            }
        }
        // mid barrier: publish P; do NOT drain vmcnt (glds stays in flight)
        asm volatile("s_waitcnt lgkmcnt(0)\n\ts_barrier" ::: "memory");
        __builtin_amdgcn_sched_barrier(0);

        if (it < ntS) {
            // ---- PV: O[32q x 128d] += P[32x64] @ V[64x128] for (term, dh) ----
            const unsigned short* Vb = (const unsigned short*)(buf + 32768);
            __builtin_amdgcn_s_setprio(1);
            #pragma unroll
            for (int ks = 0; ks < 4; ++ks) {
                s8v pa = *(const s8v*)&Ps[(term * 32 + l31) * PSTR + ks * 16 + lh * 8];
                #pragma unroll
                for (int dt = 0; dt < 4; ++dt) {
                    const int dim = kh * 128 + dt * 32 + l31;
                    const int drow = dim >> 1;
                    const int x = ((dim & 1) * 8 + ks * 2 + lh) ^ (drow & 15);
                    s8v vb = *(const s8v*)&Vb[(drow * 16 + x) * 8];
                    o[dt] = __builtin_amdgcn_mfma_f32_32x32x16_bf16(pa, vb, o[dt], 0, 0, 0);
                }
            }
            __builtin_amdgcn_s_setprio(0);
        }
        // end barrier: drains vmcnt(0) (covered by the whole tile) + lgkm;
        // next iter's QK may read the freshly staged buffer, P is free.
        __syncthreads();
    }

    // ---- finalize l per strip: intra-wave reduce, combine kh partials ----
    #pragma unroll
    for (int r = 0; r < 16; ++r) {
        float lt = l_acc[r];
        #pragma unroll
        for (int off = 1; off < 32; off <<= 1) lt += __shfl_xor(lt, off);
        if (l31 == 0) {
            const int row = (r & 3) + 8 * (r >> 2) + 4 * lh;
            Lsum[(term * 2 + kh) * 32 + row] = lt;
        }
    }
    __syncthreads();
    float inv[16];
    #pragma unroll
    for (int r = 0; r < 16; ++r) {
        const int row = (r & 3) + 8 * (r >> 2) + 4 * lh;
        inv[r] = cn / (Lsum[(term * 2 + 0) * 32 + row] + Lsum[(term * 2 + 1) * 32 + row]);
    }

    // ---- combine terms via per-strip LDS overlay (sg0->buf0, sg1->buf1) ----
    if (term) {
        #pragma unroll
        for (int dt = 0; dt < 4; ++dt)
            #pragma unroll
            for (int r = 0; r < 16; ++r) {
                const int row = (r & 3) + 8 * (r >> 2) + 4 * lh;
                Ol[row * OSTR + kh * 128 + dt * 32 + l31] = o[dt][r] * inv[r];
            }
    }
    __syncthreads();
    if (!term) {
        #pragma unroll
        for (int dt = 0; dt < 4; ++dt)
            #pragma unroll
            for (int r = 0; r < 16; ++r) {
                const int row = (r & 3) + 8 * (r >> 2) + 4 * lh;
                Ol[row * OSTR + kh * 128 + dt * 32 + l31] += o[dt][r] * inv[r];
            }
    }
    __syncthreads();
    // ---- store: each strip's 256 threads write its 32 rows ----
    #pragma unroll
    for (int rep = 0; rep < 8; ++rep) {
        int idx = (t & 255) + rep * 256;   // 32 rows x 64 float4
        int row = idx >> 6, c4 = idx & 63;
        float4 val = *(const float4*)&Ol[row * OSTR + c4 * 4];
        *(float4*)&outp[((size_t)(b * T_DIM + q0 + row)) * VD + c4 * 4] = val;
    }
}

extern "C" void kernel_launch(void* const* d_in, const int* in_sizes, int n_in,
                              void* d_out, int out_size, void* d_ws, size_t ws_size,
                              hipStream_t stream) {
    const float* x  = (const float*)d_in[0];
    const float* Wq = (const float*)d_in[1];
    const float* Wk = (const float*)d_in[2];
    const float* Wv = (const float*)d_in[3];
    const float* lq = (const float*)d_in[4];
    const float* lk = (const float*)d_in[5];
    const int* lidx = (const int*)d_in[6];

    unsigned short* ws = (unsigned short*)d_ws;
    unsigned short* qb   = ws + QB_OFF;    // [2][8][2048][128] bf16
    unsigned short* kb   = ws + KB_OFF;    // [2][8][2048][128] bf16
    unsigned short* vTb  = ws + VT_OFF;    // [8][256][2048] bf16
    unsigned short* wtb  = ws + WT_OFF;    // [768][1024] bf16
    unsigned short* xbhi = ws + XBH_OFF;   // x-bf16 rows 8192..16383
    float* lamb = (float*)(ws + LAM_OFF);
    unsigned short* xblo = (unsigned short*)d_out;  // scratch; attn overwrites d_out
    (void)ws_size; (void)in_sizes; (void)n_in; (void)out_size;

    prep_kernel<<<dim3(8961), dim3(256), 0, stream>>>(
        x, Wq, Wk, Wv, lq, lk, lidx, xblo, xbhi, wtb, lamb);
    gemm_kernel<<<dim3(128, 6), dim3(256), 0, stream>>>(xblo, xbhi, wtb, qb, kb, vTb);
    attn_kernel<<<dim3(256), dim3(512), 0, stream>>>(qb, kb, vTb, lamb, (float*)d_out);
}

// Round 11
// 200.459 us; speedup vs baseline: 1.1388x; 1.0215x over previous
//
#include <hip/hip_runtime.h>
#include <math.h>

// Problem constants
#define B_DIM 8
#define T_DIM 2048
#define C_DIM 1024
#define HS_DIM 128
#define VD 256
#define M_DIM (B_DIM * T_DIM)            // 16384 rows
#define QK_ELEMS (M_DIM * HS_DIM)        // 2,097,152 elems per (q|k) term
#define SCALE 0.088388347648318447f      // 1/sqrt(128)
#define LOG_THETA 9.210340371976184f     // ln(10000)

// workspace layout (ushort units)
#define QB_OFF   0u
#define KB_OFF   4194304u
#define VT_OFF   8388608u
#define WT_OFF   12582912u
#define XBH_OFF  13369344u               // x-bf16 rows 8192..16383
#define LAM_OFF  21757952u
#define XSPLIT_ELEMS 8388608u            // rows 0..8191 of x-bf16 live in d_out

typedef short s8v   __attribute__((ext_vector_type(8)));   // 8 bf16 (4 VGPRs)
typedef float f32x4 __attribute__((ext_vector_type(4)));
typedef float f32x16 __attribute__((ext_vector_type(16)));

// ---------- helpers ----------
__device__ __forceinline__ unsigned int bf16_rne(float f) {
    unsigned int u = __float_as_uint(f);
    return (u + 0x7fffu + ((u >> 16) & 1u)) >> 16;
}
__device__ __forceinline__ unsigned int pack_bf2(float lo, float hi) {
    return bf16_rne(lo) | (bf16_rne(hi) << 16);
}
__device__ __forceinline__ void async_cp16(const unsigned short* g, unsigned short* l) {
    __builtin_amdgcn_global_load_lds(
        (const __attribute__((address_space(1))) unsigned int*)g,
        (__attribute__((address_space(3))) unsigned int*)l, 16, 0, 0);
}

// ---------- kernel 1: fused prep (cast_x | cast_wt | lam), one dispatch ----
// blockIdx < 8192:  cast x -> bf16 (split across d_out scratch + ws)
// blockIdx < 8960:  build Wt[768][1024] bf16 (transposed, RoPE-permuted Q/K)
// blockIdx == 8960: lambda coefficients (1 wave)
__global__ __launch_bounds__(256) void prep_kernel(
    const float* __restrict__ x,
    const float* __restrict__ Wq, const float* __restrict__ Wk,
    const float* __restrict__ Wv,
    const float* __restrict__ lq, const float* __restrict__ lk,
    const int* __restrict__ lidx,
    unsigned short* __restrict__ xlo, unsigned short* __restrict__ xhi,
    unsigned short* __restrict__ wt, float* __restrict__ lam_out) {
    __shared__ float tile[32][33];
    const int bx = blockIdx.x;
    const int t = threadIdx.x;

    if (bx < 8192) {
        // ---- cast_x ----
        const size_t i8 = ((size_t)bx * 256 + t) * 8;
        float4 a = *(const float4*)(x + i8);
        float4 b = *(const float4*)(x + i8 + 4);
        uint4 u;
        u.x = pack_bf2(a.x, a.y); u.y = pack_bf2(a.z, a.w);
        u.z = pack_bf2(b.x, b.y); u.w = pack_bf2(b.z, b.w);
        unsigned short* dst = (i8 < XSPLIT_ELEMS) ? (xlo + i8) : (xhi + (i8 - XSPLIT_ELEMS));
        *(uint4*)dst = u;
    } else if (bx < 8960) {
        // ---- cast_wt: Q/K columns RoPE-permuted:
        // pi(n) = 2*((n&15)+((n>>5)<<4)) + ((n>>4)&1) per 128-col segment ----
        const int bxx = bx - 8192;
        const int n0 = (bxx % 24) * 32;
        const int k0 = (bxx / 24) * 32;
        const int seg = n0 >> 7;
        const int nl = t & 31;
        const int ng = n0 + nl;
        const int ngl = ng & 127;
        const int pcol = 2 * ((ngl & 15) + ((ngl >> 5) << 4)) + ((ngl >> 4) & 1);
        const float* src; int ld;
        if (seg < 2)      { src = Wq + (size_t)seg * (C_DIM * HS_DIM) + pcol; ld = 128; }
        else if (seg < 4) { src = Wk + (size_t)(seg - 2) * (C_DIM * HS_DIM) + pcol; ld = 128; }
        else              { src = Wv + (ng - 512); ld = 256; }
        #pragma unroll
        for (int rep = 0; rep < 4; ++rep) {
            int kl = (t >> 5) + rep * 8;
            tile[kl][nl] = src[(size_t)(k0 + kl) * ld];
        }
        __syncthreads();
        unsigned int* wt32 = (unsigned int*)wt;
        #pragma unroll
        for (int rep = 0; rep < 2; ++rep) {
            int nl2 = (t >> 4) + rep * 16;
            int k2 = (t & 15) * 2;
            unsigned int u = pack_bf2(tile[k2][nl2], tile[k2 + 1][nl2]);
            wt32[((size_t)(n0 + nl2) * 1024 + k0 + k2) >> 1] = u;
        }
    } else {
        // ---- lam (1 wave) ----
        if (t < 64) {
            float s0 = expf(lq[t] * lk[t]) + expf(lq[t + 64] * lk[t + 64]);
            float s1 = expf(lq[128 + t] * lk[128 + t]) + expf(lq[192 + t] * lk[192 + t]);
            #pragma unroll
            for (int off = 32; off > 0; off >>= 1) {
                s0 += __shfl_down(s0, off);
                s1 += __shfl_down(s1, off);
            }
            if (t == 0) {
                float e0 = s0 * (1.0f / 128.0f);
                float e1 = s1 * (1.0f / 128.0f);
                float li = 0.8f - 0.6f * expf(-0.3f * ((float)lidx[0] - 1.0f));
                lam_out[0] = e0 + li;            // +lam0
                lam_out[1] = -(e1 - e0 + li);    // -lam1
            }
        }
    }
}

// ---------- kernel 2: bf16 MFMA GEMM + RoPE / V-transpose epilogue ----------
// Round-11: R9's proven pipeline applied to the gemm K-loop. BK=64,
// DOUBLE-BUFFERED As/Bs (2 x 32 KB = 64 KB -> still 2 blocks/CU), one
// barrier per iter:
//   vmcnt(0)        <- drains only iter i-1's glds (cover = full compute(i-1))
//   s_barrier       <- publishes stage(i); all waves done compute(i-1)
//   issue glds(i+1) <- into the buffer compute(i-1) just released
//   compute buf(i)
// Replaces 2 barriers + uncovered vmcnt drain per iter (the m97-ceiling
// mechanism). Swizzle (both-sides chunk^=row&7) verbatim from round 10.
__global__ __launch_bounds__(256) void gemm_kernel(
    const unsigned short* __restrict__ xlo, const unsigned short* __restrict__ xhi,
    const unsigned short* __restrict__ wt,
    unsigned short* __restrict__ qo, unsigned short* __restrict__ ko,
    unsigned short* __restrict__ vo) {
    __shared__ unsigned short AB[2][2][128 * 64];   // [buf][A|B][128][64], 64 KB

    const int t = threadIdx.x;
    const int wv = t >> 6, lane = t & 63;
    const int quad = lane >> 4, l15 = lane & 15;
    const int m0 = blockIdx.x * 128;
    const int n0 = blockIdx.y * 128;
    const int wr = wv >> 1, wc = wv & 1;

    const unsigned short* xbase = (m0 < 8192)
        ? (xlo + (size_t)m0 * C_DIM) : (xhi + (size_t)(m0 - 8192) * C_DIM);
    const unsigned short* wbase = wt + (size_t)n0 * C_DIM;

    f32x4 acc[4][4];
    #pragma unroll
    for (int i = 0; i < 4; ++i)
        #pragma unroll
        for (int j = 0; j < 4; ++j) acc[i][j] = (f32x4){0.f, 0.f, 0.f, 0.f};

    // staging geometry: chunk ci = t + rep*256 (0..1023), row=ci>>3, slot=ci&7;
    // source col = k0 + (slot^(row&7))*8 ; LDS dst linear at ci*8 ushorts.
    int srow[4], sco[4];
    #pragma unroll
    for (int rep = 0; rep < 4; ++rep) {
        const int ci = t + rep * 256;
        srow[rep] = ci >> 3;
        sco[rep] = ((ci & 7) ^ (srow[rep] & 7)) * 8;
    }

    // ---- prologue: stage k0=0 into buf 0 ----
    #pragma unroll
    for (int rep = 0; rep < 4; ++rep) {
        const int ci = t + rep * 256;
        async_cp16(xbase + (size_t)srow[rep] * C_DIM + sco[rep], &AB[0][0][ci * 8]);
        async_cp16(wbase + (size_t)srow[rep] * C_DIM + sco[rep], &AB[0][1][ci * 8]);
    }

    for (int it = 0; it < 16; ++it) {
        const int cur = it & 1;
        // drain iter i-1's glds (prologue at it=0); cover = compute(i-1)
        asm volatile("s_waitcnt vmcnt(0)" ::: "memory");
        __builtin_amdgcn_s_barrier();
        // issue next stage into the buffer released by compute(i-1)
        if (it + 1 < 16) {
            const int kn = (it + 1) * 64;
            #pragma unroll
            for (int rep = 0; rep < 4; ++rep) {
                const int ci = t + rep * 256;
                async_cp16(xbase + (size_t)srow[rep] * C_DIM + kn + sco[rep],
                           &AB[cur ^ 1][0][ci * 8]);
                async_cp16(wbase + (size_t)srow[rep] * C_DIM + kn + sco[rep],
                           &AB[cur ^ 1][1][ci * 8]);
            }
        }
        // compute from buf[cur]
        const unsigned short* As = AB[cur][0];
        const unsigned short* Bs = AB[cur][1];
        #pragma unroll
        for (int kk = 0; kk < 2; ++kk) {
            s8v af[4], bf[4];
            #pragma unroll
            for (int i = 0; i < 4; ++i) {
                const int row = wr * 64 + i * 16 + l15;
                const int xch = (kk * 4 + quad) ^ (row & 7);
                af[i] = *(const s8v*)&As[row * 64 + xch * 8];
            }
            #pragma unroll
            for (int j = 0; j < 4; ++j) {
                const int row = wc * 64 + j * 16 + l15;
                const int xch = (kk * 4 + quad) ^ (row & 7);
                bf[j] = *(const s8v*)&Bs[row * 64 + xch * 8];
            }
            #pragma unroll
            for (int i = 0; i < 4; ++i)
                #pragma unroll
                for (int j = 0; j < 4; ++j)
                    acc[i][j] = __builtin_amdgcn_mfma_f32_16x16x32_bf16(af[i], bf[j], acc[i][j], 0, 0, 0);
        }
    }

    const int seg = n0 >> 7;   // 0..5
    if (seg < 4) {
        unsigned short* dstbuf = ((seg < 2) ? qo : ko) + (size_t)(seg & 1) * QK_ELEMS;
        // pair-index (= d>>1) for j-pairs (0,1) and (2,3)
        const int mi0 = l15 + 32 * wc;
        const int mi1 = mi0 + 16;
        const float freq0 = __expf((float)mi0 * (-LOG_THETA / 64.f));
        const float freq1 = __expf((float)mi1 * (-LOG_THETA / 64.f));
        #pragma unroll
        for (int i = 0; i < 4; ++i) {
            #pragma unroll
            for (int e = 0; e < 4; ++e) {
                const int m = m0 + wr * 64 + i * 16 + quad * 4 + e;
                const float trow = (float)(m & (T_DIM - 1));
                unsigned int* p32 = (unsigned int*)(dstbuf + (size_t)m * HS_DIM);
                float sn0, cs0, sn1, cs1;
                __sincosf(trow * freq0, &sn0, &cs0);
                __sincosf(trow * freq1, &sn1, &cs1);
                const float xr0 = acc[i][0][e], xi0 = acc[i][1][e];
                const float xr1 = acc[i][2][e], xi1 = acc[i][3][e];
                p32[mi0] = pack_bf2(xr0 * cs0 - xi0 * sn0, xr0 * sn0 + xi0 * cs0);
                p32[mi1] = pack_bf2(xr1 * cs1 - xi1 * sn1, xr1 * sn1 + xi1 * cs1);
            }
        }
    } else {
        const int bq = m0 >> 11;
        const int tbase = m0 & (T_DIM - 1);
        unsigned int* vT32 = (unsigned int*)vo;
        #pragma unroll
        for (int j = 0; j < 4; ++j) {
            const int d = (seg - 4) * 128 + wc * 64 + j * 16 + l15;
            const size_t rowbase = (size_t)(bq * VD + d) * (T_DIM / 2); // u32 units
            #pragma unroll
            for (int i = 0; i < 4; ++i) {
                const int tok = tbase + wr * 64 + i * 16 + quad * 4;
                uint2 u;
                u.x = pack_bf2(acc[i][j][0], acc[i][j][1]);
                u.y = pack_bf2(acc[i][j][2], acc[i][j][3]);
                *(uint2*)&vT32[rowbase + (tok >> 1)] = u;
            }
        }
    }
}

// ---------- kernel 3: dual-term causal attention, 32x32 bf16 MFMA ----------
// Round-9 structure (verified 64.6-68.9 us): glds double-buffered pipeline on
// the 8-wave merged block; only vmcnt(0) drain is the end-of-tile
// __syncthreads (full tile of compute cover); mid barrier is lgkmcnt-only;
// 16-slot XOR swizzle src+read (measured 0 bank conflicts).
#define PSTR 72      // P LDS row stride: 64 keys + 8 pad
#define OSTR 260     // O combine stride (fp32 words)
#define BUFB 65536   // bytes per K+V buffer
#define P_OFF 131072
#define PSZ  9216    // per-strip P region
#define SM_TOTAL 149504

__global__ __launch_bounds__(512, 1) void attn_kernel(
    const unsigned short* __restrict__ qg, const unsigned short* __restrict__ kg,
    const unsigned short* __restrict__ vg, const float* __restrict__ lam,
    float* __restrict__ outp) {
    __shared__ __align__(16) unsigned char smem[SM_TOTAL];

    const int t = threadIdx.x;
    const int id = blockIdx.x;             // 256 blocks
    const int b = id & 7;                  // batch -> XCD round-robin
    const int kp = id >> 3;                // 0..31 pair index

    const int w = t >> 6, lane = t & 63;
    const int l31 = lane & 31, lh = lane >> 5;
    const int sg = w >> 2;                 // strip slot: 0=heavy, 1=light
    const int term = w & 1;
    const int kh = (w >> 1) & 1;           // QK k-half / PV d-half

    const int strip = sg ? kp : (63 - kp);
    const int q0 = strip * 32;
    const int ntS = (strip >> 1) + 1;      // this strip's 64-key tiles
    const int ntB = ((63 - kp) >> 1) + 1;  // block tiles (heavy strip)

    unsigned short* Ps = (unsigned short*)(smem + P_OFF + sg * PSZ); // [2][32][72]
    float* Lsum = (float*)(smem + P_OFF + sg * PSZ);   // overlays dead Ps
    float* Ol = (float*)(smem + sg * BUFB);            // sg0->buf0, sg1->buf1

    const float cn = lam[term];            // lam[1] carries the minus sign

    // Q A-frags (32x32x16 layout: row=lane&31, k=lh*8+j), 8 k-steps in registers
    const unsigned short* qrow = qg
        + ((size_t)(term * B_DIM + b) * T_DIM + q0 + l31) * HS_DIM + lh * 8;
    s8v qa[8];
    #pragma unroll
    for (int ks = 0; ks < 8; ++ks)
        qa[ks] = *(const s8v*)(qrow + ks * 16);

    // ---- glds staging geometry (chunk c = t + rep*512, c in 0..2047) ----
    unsigned int kOffA[4], vOffA[4];
    #pragma unroll
    for (int rep = 0; rep < 4; ++rep) {
        const int c = t + rep * 512;
        const int rowg = c >> 4, slot = c & 15;
        const int kterm = rowg >> 6, krow = rowg & 63;
        const int kss = slot ^ (krow & 15);
        kOffA[rep] = (unsigned int)(((kterm * B_DIM + b) * T_DIM + krow) * HS_DIM
                                    + kss * 8);
        const int drow = rowg;
        const int vss = slot ^ (drow & 15);
        const int dim = 2 * drow + (vss >> 3), tokc = vss & 7;
        vOffA[rep] = (unsigned int)((b * VD + dim) * T_DIM + tokc * 8);
    }

    f32x16 o[4];
    #pragma unroll
    for (int dt = 0; dt < 4; ++dt)
        #pragma unroll
        for (int r = 0; r < 16; ++r) o[dt][r] = 0.f;
    float l_acc[16];
    #pragma unroll
    for (int r = 0; r < 16; ++r) l_acc[r] = 0.f;

    // ---- prologue: stage tile 0 into buf 0 (drain at first __syncthreads) --
    {
        unsigned short* kb0 = (unsigned short*)(smem + w * 1024);
        unsigned short* vb0 = (unsigned short*)(smem + 32768 + w * 1024);
        #pragma unroll
        for (int rep = 0; rep < 4; ++rep) {
            async_cp16(kg + kOffA[rep], kb0 + rep * 4096);
            async_cp16(vg + vOffA[rep], vb0 + rep * 4096);
        }
    }
    __syncthreads();

    const int krow = kh * 32 + l31;        // QK K row for this lane
    const int k15 = l31 & 15;

    for (int it = 0; it < ntB; ++it) {
        const int s0 = it * 64;
        const unsigned char* buf = smem + (it & 1) * BUFB;

        // ---- issue next tile's 8 glds (zero regs); drains only at the
        //      END-of-iter __syncthreads => full-tile latency cover ----
        if (it + 1 < ntB) {
            const int sn = s0 + 64;
            unsigned char* nbuf = smem + ((it + 1) & 1) * BUFB;
            unsigned short* kbn = (unsigned short*)(nbuf + w * 1024);
            unsigned short* vbn = (unsigned short*)(nbuf + 32768 + w * 1024);
            #pragma unroll
            for (int rep = 0; rep < 4; ++rep) {
                async_cp16(kg + kOffA[rep] + (size_t)sn * HS_DIM, kbn + rep * 4096);
                async_cp16(vg + vOffA[rep] + sn, vbn + rep * 4096);
            }
        }

        if (it < ntS) {                    // wave-uniform strip participation
            // ---- QK: S[32q x 32k], K rows 256B linear, 16-slot XOR reads ----
            const unsigned short* Kb = (const unsigned short*)buf;
            f32x16 sc;
            #pragma unroll
            for (int r = 0; r < 16; ++r) sc[r] = 0.f;
            __builtin_amdgcn_s_setprio(1);
            #pragma unroll
            for (int ks = 0; ks < 8; ++ks) {
                const int x = (ks * 2 + lh) ^ k15;
                s8v kf = *(const s8v*)&Kb[(term * 64 + krow) * 128 + x * 8];
                sc = __builtin_amdgcn_mfma_f32_32x32x16_bf16(qa[ks], kf, sc, 0, 0, 0);
            }
            __builtin_amdgcn_s_setprio(0);
            // exp + P write (C/D 32x32: col=l31, row=(r&3)+8*(r>>2)+4*lh)
            const int key = s0 + kh * 32 + l31;
            #pragma unroll
            for (int r = 0; r < 16; ++r) {
                const int row = (r & 3) + 8 * (r >> 2) + 4 * lh;
                const float p = (key <= q0 + row) ? __expf(sc[r] * SCALE) : 0.f;
                l_acc[r] += p;
                Ps[(term * 32 + row) * PSTR + kh * 32 + l31] = (unsigned short)bf16_rne(p);
            }
        }
        // mid barrier: publish P; do NOT drain vmcnt (glds stays in flight)
        asm volatile("s_waitcnt lgkmcnt(0)\n\ts_barrier" ::: "memory");
        __builtin_amdgcn_sched_barrier(0);

        if (it < ntS) {
            // ---- PV: O[32q x 128d] += P[32x64] @ V[64x128] for (term, dh) ----
            const unsigned short* Vb = (const unsigned short*)(buf + 32768);
            __builtin_amdgcn_s_setprio(1);
            #pragma unroll
            for (int ks = 0; ks < 4; ++ks) {
                s8v pa = *(const s8v*)&Ps[(term * 32 + l31) * PSTR + ks * 16 + lh * 8];
                #pragma unroll
                for (int dt = 0; dt < 4; ++dt) {
                    const int dim = kh * 128 + dt * 32 + l31;
                    const int drow = dim >> 1;
                    const int x = ((dim & 1) * 8 + ks * 2 + lh) ^ (drow & 15);
                    s8v vb = *(const s8v*)&Vb[(drow * 16 + x) * 8];
                    o[dt] = __builtin_amdgcn_mfma_f32_32x32x16_bf16(pa, vb, o[dt], 0, 0, 0);
                }
            }
            __builtin_amdgcn_s_setprio(0);
        }
        // end barrier: drains vmcnt(0) (covered by the whole tile) + lgkm;
        // next iter's QK may read the freshly staged buffer, P is free.
        __syncthreads();
    }

    // ---- finalize l per strip: intra-wave reduce, combine kh partials ----
    #pragma unroll
    for (int r = 0; r < 16; ++r) {
        float lt = l_acc[r];
        #pragma unroll
        for (int off = 1; off < 32; off <<= 1) lt += __shfl_xor(lt, off);
        if (l31 == 0) {
            const int row = (r & 3) + 8 * (r >> 2) + 4 * lh;
            Lsum[(term * 2 + kh) * 32 + row] = lt;
        }
    }
    __syncthreads();
    float inv[16];
    #pragma unroll
    for (int r = 0; r < 16; ++r) {
        const int row = (r & 3) + 8 * (r >> 2) + 4 * lh;
        inv[r] = cn / (Lsum[(term * 2 + 0) * 32 + row] + Lsum[(term * 2 + 1) * 32 + row]);
    }

    // ---- combine terms via per-strip LDS overlay (sg0->buf0, sg1->buf1) ----
    if (term) {
        #pragma unroll
        for (int dt = 0; dt < 4; ++dt)
            #pragma unroll
            for (int r = 0; r < 16; ++r) {
                const int row = (r & 3) + 8 * (r >> 2) + 4 * lh;
                Ol[row * OSTR + kh * 128 + dt * 32 + l31] = o[dt][r] * inv[r];
            }
    }
    __syncthreads();
    if (!term) {
        #pragma unroll
        for (int dt = 0; dt < 4; ++dt)
            #pragma unroll
            for (int r = 0; r < 16; ++r) {
                const int row = (r & 3) + 8 * (r >> 2) + 4 * lh;
                Ol[row * OSTR + kh * 128 + dt * 32 + l31] += o[dt][r] * inv[r];
            }
    }
    __syncthreads();
    // ---- store: each strip's 256 threads write its 32 rows ----
    #pragma unroll
    for (int rep = 0; rep < 8; ++rep) {
        int idx = (t & 255) + rep * 256;   // 32 rows x 64 float4
        int row = idx >> 6, c4 = idx & 63;
        float4 val = *(const float4*)&Ol[row * OSTR + c4 * 4];
        *(float4*)&outp[((size_t)(b * T_DIM + q0 + row)) * VD + c4 * 4] = val;
    }
}

extern "C" void kernel_launch(void* const* d_in, const int* in_sizes, int n_in,
                              void* d_out, int out_size, void* d_ws, size_t ws_size,
                              hipStream_t stream) {
    const float* x  = (const float*)d_in[0];
    const float* Wq = (const float*)d_in[1];
    const float* Wk = (const float*)d_in[2];
    const float* Wv = (const float*)d_in[3];
    const float* lq = (const float*)d_in[4];
    const float* lk = (const float*)d_in[5];
    const int* lidx = (const int*)d_in[6];

    unsigned short* ws = (unsigned short*)d_ws;
    unsigned short* qb   = ws + QB_OFF;    // [2][8][2048][128] bf16
    unsigned short* kb   = ws + KB_OFF;    // [2][8][2048][128] bf16
    unsigned short* vTb  = ws + VT_OFF;    // [8][256][2048] bf16
    unsigned short* wtb  = ws + WT_OFF;    // [768][1024] bf16
    unsigned short* xbhi = ws + XBH_OFF;   // x-bf16 rows 8192..16383
    float* lamb = (float*)(ws + LAM_OFF);
    unsigned short* xblo = (unsigned short*)d_out;  // scratch; attn overwrites d_out
    (void)ws_size; (void)in_sizes; (void)n_in; (void)out_size;

    prep_kernel<<<dim3(8961), dim3(256), 0, stream>>>(
        x, Wq, Wk, Wv, lq, lk, lidx, xblo, xbhi, wtb, lamb);
    gemm_kernel<<<dim3(128, 6), dim3(256), 0, stream>>>(xblo, xbhi, wtb, qb, kb, vTb);
    attn_kernel<<<dim3(256), dim3(512), 0, stream>>>(qb, kb, vTb, lamb, (float*)d_out);
}